// Round 2
// baseline (343.527 us; speedup 1.0000x reference)
//
#include <hip/hip_runtime.h>

// ---------- types ----------
typedef __attribute__((ext_vector_type(8))) short bfrag8;   // 8 bf16 bit patterns (4 VGPRs)
typedef __attribute__((ext_vector_type(4))) short bfrag4;
typedef __attribute__((ext_vector_type(4))) float f32x4;

// ---------- bf16 helpers ----------
__device__ __forceinline__ float bf2f(unsigned short h){
  unsigned u = ((unsigned)h) << 16;
  return __builtin_bit_cast(float, u);
}
__device__ __forceinline__ unsigned short f2bf(float f){
  unsigned u = __builtin_bit_cast(unsigned, f);
  u = u + 0x7FFFu + ((u >> 16) & 1u);        // round-to-nearest-even
  return (unsigned short)(u >> 16);
}
__device__ __forceinline__ bfrag8 gload8(const unsigned short* p){ // 16B-aligned global, bf16
  int4 v = *(const int4*)p;
  return __builtin_bit_cast(bfrag8, v);
}
__device__ __forceinline__ bfrag8 lds_load8(const unsigned short* p){ // 8B-aligned LDS
  bfrag4 lo = *(const bfrag4*)p;
  bfrag4 hi = *(const bfrag4*)(p + 4);
  bfrag8 r;
#pragma unroll
  for (int j = 0; j < 4; j++){ r[j] = lo[j]; r[4+j] = hi[j]; }
  return r;
}
__device__ __forceinline__ f32x4 mfma16(bfrag8 a, bfrag8 b, f32x4 c){
  return __builtin_amdgcn_mfma_f32_16x16x32_bf16(a, b, c, 0, 0, 0);
}

// ---------- dtype-dispatched input accessors (flag: 1 = tensor is f32) ----------
__device__ __forceinline__ float ldf(const void* p, size_t i, int f32){
  return f32 ? ((const float*)p)[i] : bf2f(((const unsigned short*)p)[i]);
}
__device__ __forceinline__ unsigned short ldbf(const void* p, size_t i, int f32){
  return f32 ? f2bf(((const float*)p)[i]) : ((const unsigned short*)p)[i];
}
__device__ __forceinline__ bfrag8 load8bf(const void* p, size_t base, int f32){
  if (f32){
    const float* f = (const float*)p + base;
    float4 x = *(const float4*)f;
    float4 y = *(const float4*)(f + 4);
    bfrag8 r;
    r[0]=(short)f2bf(x.x); r[1]=(short)f2bf(x.y); r[2]=(short)f2bf(x.z); r[3]=(short)f2bf(x.w);
    r[4]=(short)f2bf(y.x); r[5]=(short)f2bf(y.y); r[6]=(short)f2bf(y.z); r[7]=(short)f2bf(y.w);
    return r;
  }
  return gload8((const unsigned short*)p + base);
}

// ---------- wave reductions (plain shfl this round; DPP later once green) ----------
__device__ __forceinline__ float row16_sum(float x){
  x += __shfl_xor(x, 1, 64);
  x += __shfl_xor(x, 2, 64);
  x += __shfl_xor(x, 4, 64);
  x += __shfl_xor(x, 8, 64);
  return x;
}
__device__ __forceinline__ float xgrp_sum(float x){
  x += __shfl_xor(x, 16, 64);
  x += __shfl_xor(x, 32, 64);
  return x;
}
__device__ __forceinline__ float xgrp_max(float x){
  x = fmaxf(x, __shfl_xor(x, 16, 64));
  x = fmaxf(x, __shfl_xor(x, 32, 64));
  return x;
}

// ============================================================================
// Kernel 0: per-tensor dtype sniffing. Reading true-bf16 data as bf16 gives
// only sane exponents; f32 data read as bf16 exposes random mantissa halves
// (insane exponents) or the even-zero/odd-nonzero stride signature (exact
// values like ones). All-zero tensors are ambiguous AND dtype-irrelevant.
// ============================================================================
struct Ptrs { const void* p[21]; int n[21]; };

__device__ int classify_f32(const unsigned short* p, int n){
  int m = n < 128 ? n : 128;
  int insane = 0, evenZero = 0, evenCnt = 0, oddNZ = 0, oddCnt = 0;
  for (int i = 0; i < m; i++){
    unsigned short h = p[i];
    int e = (h >> 7) & 0xFF;
    bool z = (h & 0x7FFF) == 0;
    if (!z && (e == 0xFF || e < 90 || e > 140)) insane++;
    if (i & 1){ oddCnt++;  if (!z) oddNZ++; }
    else      { evenCnt++; if (z)  evenZero++; }
  }
  if (insane > 0) return 1;
  if (evenZero * 4 >= evenCnt * 3 && oddNZ * 4 >= oddCnt * 3) return 1;
  return 0;
}

__global__ void detect_kernel(Ptrs ptrs, int* flags){
  int t = threadIdx.x;
  if (t >= 21) return;
  if (t == 2){ flags[2] = 0; return; }   // neighbor_idx is int32
  flags[t] = classify_f32((const unsigned short*)ptrs.p[t], ptrs.n[t]);
}

// ============================================================================
// Kernel 1: q,k,v = features @ {wq,wk,wv} + bias  ->  bf16 scratch in ws.
// One wave per 16-point tile. MFMA 16x16x32 bf16.
// ============================================================================
__global__ __launch_bounds__(256)
void qkv_kernel(const void* __restrict__ feat,
                const void* __restrict__ wq, const void* __restrict__ bq,
                const void* __restrict__ wk, const void* __restrict__ bk,
                const void* __restrict__ wv, const void* __restrict__ bv,
                unsigned short* __restrict__ q_ws, unsigned short* __restrict__ k_ws,
                unsigned short* __restrict__ v_ws, const int* __restrict__ flags, int N)
{
  const int F_feat = flags[1];
  const int F_wq = flags[3], F_bq = flags[4];
  const int F_wk = flags[5], F_bk = flags[6];
  const int F_wv = flags[7], F_bv = flags[8];

  const int lane = threadIdx.x & 63;
  const int wave = threadIdx.x >> 6;
  const int o = lane >> 4, rl = lane & 15;
  const int tile = blockIdx.x * 4 + wave;
  if (tile * 16 >= N) return;

  // B fragments: B[k][n], lane holds n = rl, k = ks*32 + o*8 + j
  bfrag8 wqf[2][4], wkf[2][4], wvf[2][4];
#pragma unroll
  for (int ks = 0; ks < 2; ks++)
#pragma unroll
    for (int t = 0; t < 4; t++){
      bfrag8 a, b, c;
#pragma unroll
      for (int j = 0; j < 8; j++){
        int idx = (ks*32 + o*8 + j)*64 + t*16 + rl;
        a[j] = (short)ldbf(wq, idx, F_wq);
        b[j] = (short)ldbf(wk, idx, F_wk);
        c[j] = (short)ldbf(wv, idx, F_wv);
      }
      wqf[ks][t] = a; wkf[ks][t] = b; wvf[ks][t] = c;
    }
  float bqC[4], bkC[4], bvC[4];
#pragma unroll
  for (int t = 0; t < 4; t++){
    bqC[t] = ldf(bq, t*16+rl, F_bq);
    bkC[t] = ldf(bk, t*16+rl, F_bk);
    bvC[t] = ldf(bv, t*16+rl, F_bv);
  }

  const int n0 = tile * 16;
  // A fragments: A[m=rl][k = ks*32 + o*8 + j]  (rows = points n0..n0+15)
  bfrag8 a[2];
#pragma unroll
  for (int ks = 0; ks < 2; ks++) a[ks] = load8bf(feat, (size_t)(n0 + rl)*64 + ks*32 + o*8, F_feat);

#pragma unroll
  for (int t = 0; t < 4; t++){
    f32x4 zq = {0.f,0.f,0.f,0.f}, zk = {0.f,0.f,0.f,0.f}, zv = {0.f,0.f,0.f,0.f};
#pragma unroll
    for (int ks = 0; ks < 2; ks++){
      zq = mfma16(a[ks], wqf[ks][t], zq);
      zk = mfma16(a[ks], wkf[ks][t], zk);
      zv = mfma16(a[ks], wvf[ks][t], zv);
    }
    // D: row = o*4+q (point), col = rl; channel = t*16+rl
#pragma unroll
    for (int q = 0; q < 4; q++){
      size_t row = n0 + o*4 + q; int col = t*16 + rl;
      q_ws[row*64 + col] = f2bf(zq[q] + bqC[t]);
      k_ws[row*64 + col] = f2bf(zk[q] + bkC[t]);
      v_ws[row*64 + col] = f2bf(zv[q] + bvC[t]);
    }
  }
}

// ============================================================================
// Kernel 2: fused point-transformer. One wave per point; the K=16 neighbors
// are the M-dim of 16x16x32 bf16 MFMAs; wg1/wg2/wo live in B-fragments (VGPRs).
// ============================================================================
__global__ __launch_bounds__(256, 2)
void pt_kernel(const void* __restrict__ points,
               const void* __restrict__ feat,
               const int* __restrict__ nidx,
               const unsigned short* __restrict__ q_ws,
               const unsigned short* __restrict__ k_ws,
               const unsigned short* __restrict__ v_ws,
               const void* __restrict__ wp,  const void* __restrict__ bp,
               const void* __restrict__ gp,  const void* __restrict__ betap,
               const void* __restrict__ wg1, const void* __restrict__ bg1,
               const void* __restrict__ gg,  const void* __restrict__ betag,
               const void* __restrict__ wg2, const void* __restrict__ bg2,
               const void* __restrict__ wo,  const void* __restrict__ bo,
               const int* __restrict__ flags, void* __restrict__ out, int N)
{
  __shared__ unsigned short xbuf[4][16][68];  // per-wave C<->A layout bounce (stride 68)
  __shared__ unsigned short ybuf[4][64];

  const int F_pts = flags[0], F_feat = flags[1];
  const int F_wp  = flags[9],  F_bp  = flags[10], F_gp  = flags[11], F_bep = flags[12];
  const int F_wg1 = flags[13], F_bg1 = flags[14], F_gg  = flags[15], F_beg = flags[16];
  const int F_wg2 = flags[17], F_bg2 = flags[18], F_wo  = flags[19], F_bo  = flags[20];

  const int lane = threadIdx.x & 63;
  const int wave = threadIdx.x >> 6;
  const int o = lane >> 4, rl = lane & 15;

  // ---- per-wave constants (loaded once) ----
  bfrag8 wg1f[2][4], wg2f[2][4], wof[2][4];
#pragma unroll
  for (int ks = 0; ks < 2; ks++)
#pragma unroll
    for (int t = 0; t < 4; t++){
      bfrag8 a, b, c;
#pragma unroll
      for (int j = 0; j < 8; j++){
        int idx = (ks*32 + o*8 + j)*64 + t*16 + rl;
        a[j] = (short)ldbf(wg1, idx, F_wg1);
        b[j] = (short)ldbf(wg2, idx, F_wg2);
        c[j] = (short)ldbf(wo,  idx, F_wo);
      }
      wg1f[ks][t] = a; wg2f[ks][t] = b; wof[ks][t] = c;
    }
  bfrag8 wpf[4];
#pragma unroll
  for (int t = 0; t < 4; t++){
    bfrag8 a = {0,0,0,0,0,0,0,0};
    if (o == 0){
#pragma unroll
      for (int j = 0; j < 3; j++) a[j] = (short)ldbf(wp, j*64 + t*16 + rl, F_wp);
    }
    wpf[t] = a;
  }
  float bpC[4], gpC[4], bePC[4], bg1C[4], ggC[4], beGC[4], bg2C[4], boC[4];
#pragma unroll
  for (int t = 0; t < 4; t++){
    int c = t*16 + rl;
    bpC[t]  = ldf(bp, c, F_bp);   gpC[t]  = ldf(gp, c, F_gp);   bePC[t] = ldf(betap, c, F_bep);
    bg1C[t] = ldf(bg1, c, F_bg1); ggC[t]  = ldf(gg, c, F_gg);   beGC[t] = ldf(betag, c, F_beg);
    bg2C[t] = ldf(bg2, c, F_bg2); boC[t]  = ldf(bo, c, F_bo);
  }

  const int wstride = gridDim.x * 4;
  for (int n = blockIdx.x*4 + wave; n < N; n += wstride){
    // ---- neighbor indices ----
    const int jr = nidx[n*16 + rl];          // A-layout row m = rl
    int jq[4];
#pragma unroll
    for (int q = 0; q < 4; q++) jq[q] = nidx[n*16 + o*4 + q];   // C-layout rows

    // ---- early gathers ----
    unsigned short gvu[4][4];                 // gv C-layout: [row q][tile t]
#pragma unroll
    for (int q = 0; q < 4; q++)
#pragma unroll
      for (int t = 0; t < 4; t++) gvu[q][t] = v_ws[(size_t)jq[q]*64 + t*16 + rl];
    const float res = ldf(feat, (size_t)n*64 + lane, F_feat);
    float rel[3];
#pragma unroll
    for (int d = 0; d < 3; d++)
      rel[d] = ldf(points, (size_t)jr*3 + d, F_pts) - ldf(points, (size_t)n*3 + d, F_pts);
    bfrag8 qv[2], gkv[2];
#pragma unroll
    for (int ks = 0; ks < 2; ks++){
      qv[ks]  = gload8(q_ws + (size_t)n*64  + ks*32 + o*8);   // q[n] broadcast across rows
      gkv[ks] = gload8(k_ws + (size_t)jr*64 + ks*32 + o*8);
    }

    // ---- p = relu(LN(rel @ wp + bp)) via MFMA (K padded 3->32 with zeros) ----
    bfrag8 ap = {0,0,0,0,0,0,0,0};
    if (o == 0){
#pragma unroll
      for (int d = 0; d < 3; d++) ap[d] = (short)f2bf(rel[d]);
    }
    f32x4 pacc[4];
#pragma unroll
    for (int t = 0; t < 4; t++){
      f32x4 z = {0.f,0.f,0.f,0.f};
      pacc[t] = mfma16(ap, wpf[t], z);
    }
    float p_val[4][4];                        // [t][q], C-layout
#pragma unroll
    for (int q = 0; q < 4; q++){
      float xv[4]; float s = 0.f, s2 = 0.f;
#pragma unroll
      for (int t = 0; t < 4; t++){ xv[t] = pacc[t][q] + bpC[t]; s += xv[t]; s2 += xv[t]*xv[t]; }
      s = row16_sum(s); s2 = row16_sum(s2);
      float mu = s * (1.f/64.f);
      float var = s2 * (1.f/64.f) - mu*mu;
      float rs = rsqrtf(var + 1e-5f);
#pragma unroll
      for (int t = 0; t < 4; t++){
        float v = (xv[t] - mu) * rs * gpC[t] + bePC[t];
        p_val[t][q] = fmaxf(v, 0.f);
      }
    }

    // ---- p: C-layout -> A-layout via LDS; attn_in = q - gk + p ----
#pragma unroll
    for (int q = 0; q < 4; q++)
#pragma unroll
      for (int t = 0; t < 4; t++) xbuf[wave][o*4 + q][t*16 + rl] = f2bf(p_val[t][q]);
    bfrag8 af[2];
#pragma unroll
    for (int ks = 0; ks < 2; ks++){
      bfrag8 pA = lds_load8(&xbuf[wave][rl][ks*32 + o*8]);
      bfrag8 v;
#pragma unroll
      for (int j = 0; j < 8; j++)
        v[j] = (short)f2bf(bf2f((unsigned short)qv[ks][j]) - bf2f((unsigned short)gkv[ks][j])
                           + bf2f((unsigned short)pA[j]));
      af[ks] = v;
    }

    // ---- GEMM1 + LN + relu -> h ----
    f32x4 hacc[4] = {{0.f,0.f,0.f,0.f},{0.f,0.f,0.f,0.f},{0.f,0.f,0.f,0.f},{0.f,0.f,0.f,0.f}};
#pragma unroll
    for (int ks = 0; ks < 2; ks++)
#pragma unroll
      for (int t = 0; t < 4; t++) hacc[t] = mfma16(af[ks], wg1f[ks][t], hacc[t]);
    float h_val[4][4];
#pragma unroll
    for (int q = 0; q < 4; q++){
      float xv[4]; float s = 0.f, s2 = 0.f;
#pragma unroll
      for (int t = 0; t < 4; t++){ xv[t] = hacc[t][q] + bg1C[t]; s += xv[t]; s2 += xv[t]*xv[t]; }
      s = row16_sum(s); s2 = row16_sum(s2);
      float mu = s * (1.f/64.f);
      float var = s2 * (1.f/64.f) - mu*mu;
      float rs = rsqrtf(var + 1e-5f);
#pragma unroll
      for (int t = 0; t < 4; t++){
        float v = (xv[t] - mu) * rs * ggC[t] + beGC[t];
        h_val[t][q] = fmaxf(v, 0.f);
      }
    }

    // ---- h: C-layout -> A-layout; GEMM2 ----
#pragma unroll
    for (int q = 0; q < 4; q++)
#pragma unroll
      for (int t = 0; t < 4; t++) xbuf[wave][o*4 + q][t*16 + rl] = f2bf(h_val[t][q]);
    bfrag8 hf[2];
#pragma unroll
    for (int ks = 0; ks < 2; ks++) hf[ks] = lds_load8(&xbuf[wave][rl][ks*32 + o*8]);
    f32x4 wacc[4] = {{0.f,0.f,0.f,0.f},{0.f,0.f,0.f,0.f},{0.f,0.f,0.f,0.f},{0.f,0.f,0.f,0.f}};
#pragma unroll
    for (int ks = 0; ks < 2; ks++)
#pragma unroll
      for (int t = 0; t < 4; t++) wacc[t] = mfma16(hf[ks], wg2f[ks][t], wacc[t]);

    // ---- softmax over neighbors + weighted sum ----
    float y[4];
#pragma unroll
    for (int t = 0; t < 4; t++){
      float wv[4];
#pragma unroll
      for (int q = 0; q < 4; q++) wv[q] = wacc[t][q] + bg2C[t];
      float mx = fmaxf(fmaxf(wv[0], wv[1]), fmaxf(wv[2], wv[3]));
      mx = xgrp_max(mx);
      float se = 0.f, z = 0.f;
#pragma unroll
      for (int q = 0; q < 4; q++){
        float e = __expf(wv[q] - mx);
        se += e;
        z  += e * (bf2f(gvu[q][t]) + p_val[t][q]);
      }
      se = xgrp_sum(se); z = xgrp_sum(z);
      y[t] = z / se;
    }

    // ---- out = y @ wo + bo + residual ----
    if (o == 0){
#pragma unroll
      for (int t = 0; t < 4; t++) ybuf[wave][t*16 + rl] = f2bf(y[t]);
    }
    bfrag8 yf[2];
#pragma unroll
    for (int ks = 0; ks < 2; ks++) yf[ks] = lds_load8(&ybuf[wave][ks*32 + o*8]);
    f32x4 oacc[4] = {{0.f,0.f,0.f,0.f},{0.f,0.f,0.f,0.f},{0.f,0.f,0.f,0.f},{0.f,0.f,0.f,0.f}};
#pragma unroll
    for (int ks = 0; ks < 2; ks++)
#pragma unroll
      for (int t = 0; t < 4; t++) oacc[t] = mfma16(yf[ks], wof[ks][t], oacc[t]);

    float ov = 0.f;
#pragma unroll
    for (int t = 0; t < 4; t++) if (o == t) ov = oacc[t][0] + boC[t];
    float outv = ov + res;
    if (F_feat) ((float*)out)[(size_t)n*64 + lane] = outv;        // f32 chain -> f32 out
    else ((unsigned short*)out)[(size_t)n*64 + lane] = f2bf(outv); // bf16 out
  }
}

// ============================================================================
extern "C" void kernel_launch(void* const* d_in, const int* in_sizes, int n_in,
                              void* d_out, int out_size, void* d_ws, size_t ws_size,
                              hipStream_t stream)
{
  const int N = in_sizes[1] / 64;

  unsigned short* q_ws = (unsigned short*)d_ws;
  unsigned short* k_ws = q_ws + (size_t)N * 64;
  unsigned short* v_ws = k_ws + (size_t)N * 64;
  int* flags = (int*)((char*)d_ws + (size_t)3 * N * 64 * sizeof(unsigned short));

  Ptrs ptrs;
  for (int i = 0; i < 21; i++){ ptrs.p[i] = d_in[i]; ptrs.n[i] = in_sizes[i]; }
  detect_kernel<<<1, 64, 0, stream>>>(ptrs, flags);

  const int tiles = (N + 15) / 16;
  qkv_kernel<<<(tiles + 3) / 4, 256, 0, stream>>>(d_in[1], d_in[3], d_in[4], d_in[5], d_in[6],
                                                  d_in[7], d_in[8], q_ws, k_ws, v_ws, flags, N);
  pt_kernel<<<512, 256, 0, stream>>>(d_in[0], d_in[1], (const int*)d_in[2], q_ws, k_ws, v_ws,
                                     d_in[9], d_in[10], d_in[11], d_in[12],
                                     d_in[13], d_in[14], d_in[15], d_in[16],
                                     d_in[17], d_in[18], d_in[19], d_in[20],
                                     flags, d_out, N);
}

// Round 3
// 285.327 us; speedup vs baseline: 1.2040x; 1.2040x over previous
//
#include <hip/hip_runtime.h>

// ---------- types ----------
typedef __attribute__((ext_vector_type(8))) short bfrag8;   // 8 bf16 bit patterns (4 VGPRs)
typedef __attribute__((ext_vector_type(4))) short bfrag4;
typedef __attribute__((ext_vector_type(4))) float f32x4;

// ---------- bf16 helpers ----------
__device__ __forceinline__ float bf2f(unsigned short h){
  unsigned u = ((unsigned)h) << 16;
  return __builtin_bit_cast(float, u);
}
__device__ __forceinline__ unsigned short f2bf(float f){
  unsigned u = __builtin_bit_cast(unsigned, f);
  u = u + 0x7FFFu + ((u >> 16) & 1u);        // round-to-nearest-even
  return (unsigned short)(u >> 16);
}
__device__ __forceinline__ bfrag8 gload8(const unsigned short* p){ // 16B-aligned global, bf16
  int4 v = *(const int4*)p;
  return __builtin_bit_cast(bfrag8, v);
}
__device__ __forceinline__ bfrag8 lds_load8(const unsigned short* p){ // 8B-aligned LDS
  bfrag4 lo = *(const bfrag4*)p;
  bfrag4 hi = *(const bfrag4*)(p + 4);
  bfrag8 r;
#pragma unroll
  for (int j = 0; j < 4; j++){ r[j] = lo[j]; r[4+j] = hi[j]; }
  return r;
}
__device__ __forceinline__ f32x4 mfma16(bfrag8 a, bfrag8 b, f32x4 c){
  return __builtin_amdgcn_mfma_f32_16x16x32_bf16(a, b, c, 0, 0, 0);
}

// ---------- dtype-dispatched accessors (flag: 1 = tensor is f32) ----------
__device__ __forceinline__ float ldf(const void* p, size_t i, int f32){
  return f32 ? ((const float*)p)[i] : bf2f(((const unsigned short*)p)[i]);
}
__device__ __forceinline__ unsigned short ldbf(const void* p, size_t i, int f32){
  return f32 ? f2bf(((const float*)p)[i]) : ((const unsigned short*)p)[i];
}
__device__ __forceinline__ bfrag8 load8bf(const void* p, size_t base, int f32){
  if (f32){
    const float* f = (const float*)p + base;
    float4 x = *(const float4*)f;
    float4 y = *(const float4*)(f + 4);
    bfrag8 r;
    r[0]=(short)f2bf(x.x); r[1]=(short)f2bf(x.y); r[2]=(short)f2bf(x.z); r[3]=(short)f2bf(x.w);
    r[4]=(short)f2bf(y.x); r[5]=(short)f2bf(y.y); r[6]=(short)f2bf(y.z); r[7]=(short)f2bf(y.w);
    return r;
  }
  return gload8((const unsigned short*)p + base);
}

// ---------- wave reductions ----------
__device__ __forceinline__ float row16_sum(float x){
  x += __shfl_xor(x, 1, 64);
  x += __shfl_xor(x, 2, 64);
  x += __shfl_xor(x, 4, 64);
  x += __shfl_xor(x, 8, 64);
  return x;
}
__device__ __forceinline__ float xgrp_sum(float x){
  x += __shfl_xor(x, 16, 64);
  x += __shfl_xor(x, 32, 64);
  return x;
}
__device__ __forceinline__ float xgrp_max(float x){
  x = fmaxf(x, __shfl_xor(x, 16, 64));
  x = fmaxf(x, __shfl_xor(x, 32, 64));
  return x;
}

// ============================================================================
// Kernel 0: per-tensor dtype sniffing (see round-1 notes).
// ============================================================================
struct Ptrs { const void* p[21]; int n[21]; };

__device__ int classify_f32(const unsigned short* p, int n){
  int m = n < 128 ? n : 128;
  int insane = 0, evenZero = 0, evenCnt = 0, oddNZ = 0, oddCnt = 0;
  for (int i = 0; i < m; i++){
    unsigned short h = p[i];
    int e = (h >> 7) & 0xFF;
    bool z = (h & 0x7FFF) == 0;
    if (!z && (e == 0xFF || e < 90 || e > 140)) insane++;
    if (i & 1){ oddCnt++;  if (!z) oddNZ++; }
    else      { evenCnt++; if (z)  evenZero++; }
  }
  if (insane > 0) return 1;
  if (evenZero * 4 >= evenCnt * 3 && oddNZ * 4 >= oddCnt * 3) return 1;
  return 0;
}

__global__ void detect_kernel(Ptrs ptrs, int* flags){
  int t = threadIdx.x;
  if (t >= 21) return;
  if (t == 2){ flags[2] = 0; return; }   // neighbor_idx is int32
  flags[t] = classify_f32((const unsigned short*)ptrs.p[t], ptrs.n[t]);
}

// ============================================================================
// Kernel 0b: canonicalize params. Weights -> fragment-ordered bf16
// (one 16B load per fragment in the hot kernels); biases/scales -> f32.
// ============================================================================
struct PrepPtrs { const void* w[6]; const void* wp; const void* b[11]; };

__global__ void prep_kernel(PrepPtrs pp, const int* __restrict__ flags,
                            unsigned short* __restrict__ wfrag,
                            unsigned short* __restrict__ wp_bf,
                            float* __restrict__ biases)
{
  const int tid = threadIdx.x;
  const int wflag[6] = {3,5,7,13,17,19};          // wq,wk,wv,wg1,wg2,wo
  for (int idx = tid; idx < 6*4096; idx += 256){
    int m = idx >> 12;
    int r = idx & 4095;          // ((ks*4+t)*64 + lane)*8 + j
    int j = r & 7;
    int lane = (r >> 3) & 63;
    int kt = r >> 9;
    int ks = kt >> 2, t = kt & 3;
    int o = lane >> 4, rl = lane & 15;
    int src = (ks*32 + o*8 + j)*64 + t*16 + rl;   // B[k][n] fragment element
    wfrag[idx] = ldbf(pp.w[m], src, flags[wflag[m]]);
  }
  for (int i = tid; i < 192; i += 256) wp_bf[i] = ldbf(pp.wp, i, flags[9]);
  const int bflag[11] = {4,6,8,10,11,12,14,15,16,18,20}; // bq,bk,bv,bp,gp,betap,bg1,gg,betag,bg2,bo
  for (int i = tid; i < 11*64; i += 256){
    int m = i >> 6;
    biases[i] = ldf(pp.b[m], i & 63, flags[bflag[m]]);
  }
}

// ============================================================================
// Kernel 1: q,k,v = features @ {wq,wk,wv} + bias  ->  bf16 scratch in ws.
// ============================================================================
__global__ __launch_bounds__(256)
void qkv_kernel(const void* __restrict__ feat,
                const unsigned short* __restrict__ wfrag,
                const float* __restrict__ biases,
                unsigned short* __restrict__ q_ws, unsigned short* __restrict__ k_ws,
                unsigned short* __restrict__ v_ws, const int* __restrict__ flags, int N)
{
  const int F_feat = flags[1];
  const int lane = threadIdx.x & 63;
  const int wave = threadIdx.x >> 6;
  const int o = lane >> 4, rl = lane & 15;
  const int tile = blockIdx.x * 4 + wave;
  if (tile * 16 >= N) return;

  const unsigned short* wqF = wfrag;
  const unsigned short* wkF = wfrag + 4096;
  const unsigned short* wvF = wfrag + 8192;

  bfrag8 wqf[2][4], wkf[2][4], wvf[2][4];
#pragma unroll
  for (int ks = 0; ks < 2; ks++)
#pragma unroll
    for (int t = 0; t < 4; t++){
      int off = ((ks*4 + t)*64 + lane)*8;
      wqf[ks][t] = gload8(wqF + off);
      wkf[ks][t] = gload8(wkF + off);
      wvf[ks][t] = gload8(wvF + off);
    }
  float bqC[4], bkC[4], bvC[4];
#pragma unroll
  for (int t = 0; t < 4; t++){
    bqC[t] = biases[0*64 + t*16 + rl];
    bkC[t] = biases[1*64 + t*16 + rl];
    bvC[t] = biases[2*64 + t*16 + rl];
  }

  const int n0 = tile * 16;
  bfrag8 a[2];
#pragma unroll
  for (int ks = 0; ks < 2; ks++) a[ks] = load8bf(feat, (size_t)(n0 + rl)*64 + ks*32 + o*8, F_feat);

#pragma unroll
  for (int t = 0; t < 4; t++){
    f32x4 zq = {0.f,0.f,0.f,0.f}, zk = {0.f,0.f,0.f,0.f}, zv = {0.f,0.f,0.f,0.f};
#pragma unroll
    for (int ks = 0; ks < 2; ks++){
      zq = mfma16(a[ks], wqf[ks][t], zq);
      zk = mfma16(a[ks], wkf[ks][t], zk);
      zv = mfma16(a[ks], wvf[ks][t], zv);
    }
#pragma unroll
    for (int q = 0; q < 4; q++){
      size_t row = n0 + o*4 + q; int col = t*16 + rl;
      q_ws[row*64 + col] = f2bf(zq[q] + bqC[t]);
      k_ws[row*64 + col] = f2bf(zk[q] + bkC[t]);
      v_ws[row*64 + col] = f2bf(zv[q] + bvC[t]);
    }
  }
}

// ============================================================================
// Kernel 2: fused point-transformer. One wave per point; K=16 neighbors are
// the M-dim of 16x16x32 bf16 MFMAs; wg1/wg2/wo in B-fragments (VGPRs).
// ============================================================================
__global__ __launch_bounds__(256, 2)
void pt_kernel(const void* __restrict__ points,
               const void* __restrict__ feat,
               const int* __restrict__ nidx,
               const unsigned short* __restrict__ q_ws,
               const unsigned short* __restrict__ k_ws,
               const unsigned short* __restrict__ v_ws,
               const unsigned short* __restrict__ wfrag,
               const unsigned short* __restrict__ wp_bf,
               const float* __restrict__ biases,
               const int* __restrict__ flags, void* __restrict__ out, int N)
{
  __shared__ unsigned short xbuf[4][16][68];  // per-wave C<->A bounce (stride 68)
  __shared__ unsigned short ybuf[4][64];

  const int F_pts = flags[0], F_feat = flags[1];
  const int lane = threadIdx.x & 63;
  const int wave = threadIdx.x >> 6;
  const int o = lane >> 4, rl = lane & 15;

  // ---- per-wave constants (one 16B load per fragment) ----
  const unsigned short* wg1F = wfrag + 3*4096;
  const unsigned short* wg2F = wfrag + 4*4096;
  const unsigned short* woF  = wfrag + 5*4096;
  bfrag8 wg1f[2][4], wg2f[2][4], wof[2][4];
#pragma unroll
  for (int ks = 0; ks < 2; ks++)
#pragma unroll
    for (int t = 0; t < 4; t++){
      int off = ((ks*4 + t)*64 + lane)*8;
      wg1f[ks][t] = gload8(wg1F + off);
      wg2f[ks][t] = gload8(wg2F + off);
      wof[ks][t]  = gload8(woF  + off);
    }
  bfrag8 wpf[4];
#pragma unroll
  for (int t = 0; t < 4; t++){
    bfrag8 a = {0,0,0,0,0,0,0,0};
    if (o == 0){
#pragma unroll
      for (int j = 0; j < 3; j++) a[j] = (short)wp_bf[j*64 + t*16 + rl];
    }
    wpf[t] = a;
  }
  float bpC[4], gpC[4], bePC[4], bg1C[4], ggC[4], beGC[4], bg2C[4], boC[4];
#pragma unroll
  for (int t = 0; t < 4; t++){
    int c = t*16 + rl;
    bpC[t]  = biases[3*64 + c];  gpC[t]  = biases[4*64 + c];  bePC[t] = biases[5*64 + c];
    bg1C[t] = biases[6*64 + c];  ggC[t]  = biases[7*64 + c];  beGC[t] = biases[8*64 + c];
    bg2C[t] = biases[9*64 + c];  boC[t]  = biases[10*64 + c];
  }

  const int wstride = gridDim.x * 4;
  for (int n = blockIdx.x*4 + wave; n < N; n += wstride){
    const int jr = nidx[n*16 + rl];          // A-layout row m = rl
    int jq[4];
#pragma unroll
    for (int q = 0; q < 4; q++) jq[q] = nidx[n*16 + o*4 + q];   // C-layout rows

    unsigned short gvu[4][4];                 // gv C-layout: [row q][tile t]
#pragma unroll
    for (int q = 0; q < 4; q++)
#pragma unroll
      for (int t = 0; t < 4; t++) gvu[q][t] = v_ws[(size_t)jq[q]*64 + t*16 + rl];
    const float res = ldf(feat, (size_t)n*64 + lane, F_feat);
    float rel[3];
#pragma unroll
    for (int d = 0; d < 3; d++)
      rel[d] = ldf(points, (size_t)jr*3 + d, F_pts) - ldf(points, (size_t)n*3 + d, F_pts);
    bfrag8 qv[2], gkv[2];
#pragma unroll
    for (int ks = 0; ks < 2; ks++){
      qv[ks]  = gload8(q_ws + (size_t)n*64  + ks*32 + o*8);
      gkv[ks] = gload8(k_ws + (size_t)jr*64 + ks*32 + o*8);
    }

    // ---- p = relu(LN(rel @ wp + bp)) via MFMA (K padded 3->32) ----
    bfrag8 ap = {0,0,0,0,0,0,0,0};
    if (o == 0){
#pragma unroll
      for (int d = 0; d < 3; d++) ap[d] = (short)f2bf(rel[d]);
    }
    f32x4 pacc[4];
#pragma unroll
    for (int t = 0; t < 4; t++){
      f32x4 z = {0.f,0.f,0.f,0.f};
      pacc[t] = mfma16(ap, wpf[t], z);
    }
    float p_val[4][4];                        // [t][q], C-layout
#pragma unroll
    for (int q = 0; q < 4; q++){
      float xv[4]; float s = 0.f, s2 = 0.f;
#pragma unroll
      for (int t = 0; t < 4; t++){ xv[t] = pacc[t][q] + bpC[t]; s += xv[t]; s2 += xv[t]*xv[t]; }
      s = row16_sum(s); s2 = row16_sum(s2);
      float mu = s * (1.f/64.f);
      float var = s2 * (1.f/64.f) - mu*mu;
      float rs = rsqrtf(var + 1e-5f);
#pragma unroll
      for (int t = 0; t < 4; t++){
        float v = (xv[t] - mu) * rs * gpC[t] + bePC[t];
        p_val[t][q] = fmaxf(v, 0.f);
      }
    }

    // ---- p: C->A via LDS; attn_in = q - gk + p ----
#pragma unroll
    for (int q = 0; q < 4; q++)
#pragma unroll
      for (int t = 0; t < 4; t++) xbuf[wave][o*4 + q][t*16 + rl] = f2bf(p_val[t][q]);
    bfrag8 af[2];
#pragma unroll
    for (int ks = 0; ks < 2; ks++){
      bfrag8 pA = lds_load8(&xbuf[wave][rl][ks*32 + o*8]);
      bfrag8 v;
#pragma unroll
      for (int j = 0; j < 8; j++)
        v[j] = (short)f2bf(bf2f((unsigned short)qv[ks][j]) - bf2f((unsigned short)gkv[ks][j])
                           + bf2f((unsigned short)pA[j]));
      af[ks] = v;
    }

    // ---- GEMM1 + LN + relu -> h ----
    f32x4 hacc[4] = {{0.f,0.f,0.f,0.f},{0.f,0.f,0.f,0.f},{0.f,0.f,0.f,0.f},{0.f,0.f,0.f,0.f}};
#pragma unroll
    for (int ks = 0; ks < 2; ks++)
#pragma unroll
      for (int t = 0; t < 4; t++) hacc[t] = mfma16(af[ks], wg1f[ks][t], hacc[t]);
    float h_val[4][4];
#pragma unroll
    for (int q = 0; q < 4; q++){
      float xv[4]; float s = 0.f, s2 = 0.f;
#pragma unroll
      for (int t = 0; t < 4; t++){ xv[t] = hacc[t][q] + bg1C[t]; s += xv[t]; s2 += xv[t]*xv[t]; }
      s = row16_sum(s); s2 = row16_sum(s2);
      float mu = s * (1.f/64.f);
      float var = s2 * (1.f/64.f) - mu*mu;
      float rs = rsqrtf(var + 1e-5f);
#pragma unroll
      for (int t = 0; t < 4; t++){
        float v = (xv[t] - mu) * rs * ggC[t] + beGC[t];
        h_val[t][q] = fmaxf(v, 0.f);
      }
    }

    // ---- h: C->A; GEMM2 ----
#pragma unroll
    for (int q = 0; q < 4; q++)
#pragma unroll
      for (int t = 0; t < 4; t++) xbuf[wave][o*4 + q][t*16 + rl] = f2bf(h_val[t][q]);
    bfrag8 hf[2];
#pragma unroll
    for (int ks = 0; ks < 2; ks++) hf[ks] = lds_load8(&xbuf[wave][rl][ks*32 + o*8]);
    f32x4 wacc[4] = {{0.f,0.f,0.f,0.f},{0.f,0.f,0.f,0.f},{0.f,0.f,0.f,0.f},{0.f,0.f,0.f,0.f}};
#pragma unroll
    for (int ks = 0; ks < 2; ks++)
#pragma unroll
      for (int t = 0; t < 4; t++) wacc[t] = mfma16(hf[ks], wg2f[ks][t], wacc[t]);

    // ---- softmax over neighbors + weighted sum ----
    float y[4];
#pragma unroll
    for (int t = 0; t < 4; t++){
      float wv[4];
#pragma unroll
      for (int q = 0; q < 4; q++) wv[q] = wacc[t][q] + bg2C[t];
      float mx = fmaxf(fmaxf(wv[0], wv[1]), fmaxf(wv[2], wv[3]));
      mx = xgrp_max(mx);
      float se = 0.f, z = 0.f;
#pragma unroll
      for (int q = 0; q < 4; q++){
        float e = __expf(wv[q] - mx);
        se += e;
        z  += e * (bf2f(gvu[q][t]) + p_val[t][q]);
      }
      se = xgrp_sum(se); z = xgrp_sum(z);
      y[t] = z / se;
    }

    // ---- out = y @ wo + bo + residual ----
    if (o == 0){
#pragma unroll
      for (int t = 0; t < 4; t++) ybuf[wave][t*16 + rl] = f2bf(y[t]);
    }
    bfrag8 yf[2];
#pragma unroll
    for (int ks = 0; ks < 2; ks++) yf[ks] = lds_load8(&ybuf[wave][ks*32 + o*8]);
    f32x4 oacc[4] = {{0.f,0.f,0.f,0.f},{0.f,0.f,0.f,0.f},{0.f,0.f,0.f,0.f},{0.f,0.f,0.f,0.f}};
#pragma unroll
    for (int ks = 0; ks < 2; ks++)
#pragma unroll
      for (int t = 0; t < 4; t++) oacc[t] = mfma16(yf[ks], wof[ks][t], oacc[t]);

    float ov = 0.f;
#pragma unroll
    for (int t = 0; t < 4; t++) if (o == t) ov = oacc[t][0] + boC[t];
    float outv = ov + res;
    if (F_feat) ((float*)out)[(size_t)n*64 + lane] = outv;
    else ((unsigned short*)out)[(size_t)n*64 + lane] = f2bf(outv);
  }
}

// ============================================================================
extern "C" void kernel_launch(void* const* d_in, const int* in_sizes, int n_in,
                              void* d_out, int out_size, void* d_ws, size_t ws_size,
                              hipStream_t stream)
{
  const int N = in_sizes[1] / 64;

  unsigned short* q_ws = (unsigned short*)d_ws;
  unsigned short* k_ws = q_ws + (size_t)N * 64;
  unsigned short* v_ws = k_ws + (size_t)N * 64;
  char* base = (char*)d_ws + (size_t)3 * N * 64 * sizeof(unsigned short);
  int*            flags  = (int*)base;                          // 128 B
  unsigned short* wfrag  = (unsigned short*)(base + 256);       // 6*4096*2 = 49152 B
  unsigned short* wp_bf  = (unsigned short*)(base + 256 + 49152); // 384 B (pad 512)
  float*          biases = (float*)(base + 256 + 49152 + 512);  // 11*64*4 = 2816 B

  Ptrs ptrs;
  for (int i = 0; i < 21; i++){ ptrs.p[i] = d_in[i]; ptrs.n[i] = in_sizes[i]; }
  detect_kernel<<<1, 64, 0, stream>>>(ptrs, flags);

  PrepPtrs pp;
  pp.w[0] = d_in[3];  pp.w[1] = d_in[5];  pp.w[2] = d_in[7];
  pp.w[3] = d_in[13]; pp.w[4] = d_in[17]; pp.w[5] = d_in[19];
  pp.wp = d_in[9];
  pp.b[0] = d_in[4];  pp.b[1] = d_in[6];  pp.b[2] = d_in[8];  pp.b[3] = d_in[10];
  pp.b[4] = d_in[11]; pp.b[5] = d_in[12]; pp.b[6] = d_in[14]; pp.b[7] = d_in[15];
  pp.b[8] = d_in[16]; pp.b[9] = d_in[18]; pp.b[10] = d_in[20];
  prep_kernel<<<1, 256, 0, stream>>>(pp, flags, wfrag, wp_bf, biases);

  const int tiles = (N + 15) / 16;
  qkv_kernel<<<(tiles + 3) / 4, 256, 0, stream>>>(d_in[1], wfrag, biases,
                                                  q_ws, k_ws, v_ws, flags, N);
  pt_kernel<<<1024, 256, 0, stream>>>(d_in[0], d_in[1], (const int*)d_in[2], q_ws, k_ws, v_ws,
                                      wfrag, wp_bf, biases, flags, d_out, N);
}